// Round 3
// baseline (330.030 us; speedup 1.0000x reference)
//
#include <hip/hip_runtime.h>
#include <math.h>

#define LSEQ 8192
#define TS   32
#define NST  8

// ---------------------------------------------------------------------------
// DPP 16-lane reduction. xor1=quad_perm 0xB1, xor2=0x4E, row_ror:8, row_ror:4.
// ---------------------------------------------------------------------------
template<int CTRL>
__device__ __forceinline__ float dpp_add(float x) {
  const int y = __builtin_amdgcn_update_dpp(0, __float_as_int(x), CTRL, 0xF, 0xF, true);
  return x + __int_as_float(y);
}
__device__ __forceinline__ float red16(float x) {
  x = dpp_add<0xB1>(x);
  x = dpp_add<0x4E>(x);
  x = dpp_add<0x128>(x);
  x = dpp_add<0x124>(x);
  return x;
}

// ---------------------------------------------------------------------------
// K0: transpose x_proj weights to [dir][k=192][40] (r-minor, padded) for s_load
// ---------------------------------------------------------------------------
__global__ __launch_bounds__(256) void k0_wt(const float* __restrict__ xw_f,
    const float* __restrict__ xw_b, float* __restrict__ xwT) {
  for (int idx = threadIdx.x; idx < 2 * 192 * 40; idx += 256) {
    const int dir = idx / (192 * 40), rem = idx - dir * 192 * 40;
    const int k = rem / 40, r = rem - k * 40;
    const float* w = dir ? xw_b : xw_f;
    xwT[idx] = (r < 38) ? w[r * 192 + k] : 0.f;
  }
}

// ---------------------------------------------------------------------------
// K1: serpentine gather + LayerNorm over C=96.  out: xn[(b*L+l)*96 + c]
// ---------------------------------------------------------------------------
__global__ __launch_bounds__(256) void k1_serp_ln(const float* __restrict__ x,
    const float* __restrict__ gam, const float* __restrict__ bet,
    float* __restrict__ xn) {
  const int b  = blockIdx.x >> 7;
  const int l0 = (blockIdx.x & 127) << 6;
  __shared__ float xs[96][65];
  __shared__ float mu[64], rs[64];
  const int tid = threadIdx.x;
  for (int idx = tid; idx < 96 * 64; idx += 256) {
    const int c = idx >> 6, l = idx & 63;
    const int lg = l0 + l;
    const int hh = (lg >> 5) & 31, w = lg & 31;
    const int lsrc = (hh & 1) ? (lg + 31 - 2 * w) : lg;
    xs[c][l] = x[(b * 96 + c) * LSEQ + lsrc];
  }
  __syncthreads();
  {
    const int l = tid >> 2, k = tid & 3;
    float s = 0.f, s2 = 0.f;
    for (int c = k; c < 96; c += 4) { const float v = xs[c][l]; s += v; s2 += v * v; }
    s  += __shfl_xor(s, 1);  s  += __shfl_xor(s, 2);
    s2 += __shfl_xor(s2, 1); s2 += __shfl_xor(s2, 2);
    if (k == 0) {
      const float m = s * (1.f / 96.f);
      const float var = s2 * (1.f / 96.f) - m * m;
      mu[l] = m; rs[l] = rsqrtf(var + 1e-5f);
    }
  }
  __syncthreads();
  for (int idx = tid; idx < 64 * 96; idx += 256) {
    const int l = idx / 96, c = idx - l * 96;
    xn[((size_t)b * LSEQ + l0) * 96 + idx] = (xs[c][l] - mu[l]) * rs[l] * gam[c] + bet[c];
  }
}

// ---------------------------------------------------------------------------
// K2: in_proj GEMM  M=16384 x N=384, K=96.  Writes transposed xz[b][e][l];
//     silu applied for e>=192 (the z half).
// ---------------------------------------------------------------------------
__global__ __launch_bounds__(256) void k2_inproj(const float* __restrict__ xn,
    const float* __restrict__ W, float* __restrict__ xz) {
  const int m0 = blockIdx.x << 6;
  const int e0 = blockIdx.y << 6;
  __shared__ float As[96][67];
  __shared__ float Ws[96][67];
  const int tid = threadIdx.x;
  for (int idx = tid; idx < 64 * 96; idx += 256) {
    const int r = idx / 96, k = idx - r * 96;
    As[k][r] = xn[(size_t)m0 * 96 + idx];
    Ws[k][r] = W[(size_t)e0 * 96 + idx];
  }
  __syncthreads();
  const int tx = tid & 15, ty = tid >> 4;
  const int la = tx << 2, ea = ty << 2;
  float acc[4][4] = {};
  for (int k = 0; k < 96; ++k) {
    float av[4], bv[4];
#pragma unroll
    for (int i = 0; i < 4; ++i) av[i] = As[k][la + i];
#pragma unroll
    for (int j = 0; j < 4; ++j) bv[j] = Ws[k][ea + j];
#pragma unroll
    for (int j = 0; j < 4; ++j)
#pragma unroll
      for (int i = 0; i < 4; ++i) acc[j][i] = fmaf(bv[j], av[i], acc[j][i]);
  }
  const int b = m0 >> 13, l0 = m0 & (LSEQ - 1);
  const bool dos = (e0 >= 192);
#pragma unroll
  for (int j = 0; j < 4; ++j) {
    const int e = e0 + ea + j;
    float4 v;
    v.x = acc[j][0]; v.y = acc[j][1]; v.z = acc[j][2]; v.w = acc[j][3];
    if (dos) {
      v.x = v.x / (1.f + __expf(-v.x)); v.y = v.y / (1.f + __expf(-v.y));
      v.z = v.z / (1.f + __expf(-v.z)); v.w = v.w / (1.f + __expf(-v.w));
    }
    *(float4*)(&xz[((size_t)b * 384 + e) * LSEQ + l0 + la]) = v;
  }
}

// ---------------------------------------------------------------------------
// K3a: depthwise conv + silu for BOTH directions (shared xz read).
//      xc[dirb][d][l], dirb = dir*2 + b.
// ---------------------------------------------------------------------------
__global__ __launch_bounds__(256) void k3a_conv(const float* __restrict__ xz,
    const float* __restrict__ cw_f, const float* __restrict__ cb_f,
    const float* __restrict__ cw_b, const float* __restrict__ cb_b,
    float* __restrict__ xc) {
  const int l = (blockIdx.x << 8) + threadIdx.x;
  const int d = blockIdx.y, b = blockIdx.z;
  const float* xin = xz + ((size_t)b * 384 + d) * LSEQ;
  float xv[7];
#pragma unroll
  for (int j = -3; j <= 3; ++j) {
    const int ls = l + j;
    xv[j + 3] = ((unsigned)ls < LSEQ) ? xin[ls] : 0.f;
  }
  float af = cb_f[d], ab = cb_b[d];
#pragma unroll
  for (int j = 0; j < 4; ++j) {
    af = fmaf(cw_f[d * 4 + j], xv[j], af);       // x[l-3+j]
    ab = fmaf(cw_b[d * 4 + j], xv[6 - j], ab);   // x[l+3-j]
  }
  xc[((size_t)(b)       * 192 + d) * LSEQ + l] = af / (1.f + __expf(-af));
  xc[((size_t)(2 + b)   * 192 + d) * LSEQ + l] = ab / (1.f + __expf(-ab));
}

// ---------------------------------------------------------------------------
// K3b: x_proj — lanes = l columns, weights via wave-uniform (scalar) loads,
//      38 VGPR accumulators.  Writes BC interleaved + dbl6 rows.
// ---------------------------------------------------------------------------
__global__ __launch_bounds__(128) void k3b_xproj(const float* __restrict__ xc,
    const float* __restrict__ xwT, float* __restrict__ dbl6,
    float* __restrict__ BCo) {
  const int dirb = blockIdx.y, dir = dirb >> 1;
  const int l = (blockIdx.x << 7) + threadIdx.x;
  const float* pc = xc + (size_t)dirb * 192 * LSEQ + l;
  const float* w = xwT + dir * 192 * 40;
  float acc[38];
#pragma unroll
  for (int r = 0; r < 38; ++r) acc[r] = 0.f;
#pragma unroll 2
  for (int k = 0; k < 192; ++k) {
    const float v = pc[(size_t)k * LSEQ];
    const float* wk = w + k * 40;
#pragma unroll
    for (int r = 0; r < 38; ++r) acc[r] = fmaf(wk[r], v, acc[r]);
  }
#pragma unroll
  for (int r = 0; r < 6; ++r) dbl6[((size_t)dirb * 6 + r) * LSEQ + l] = acc[r];
  float4* pbc = (float4*)(BCo + ((size_t)dirb * LSEQ + l) * 32);
#pragma unroll
  for (int j = 0; j < 8; ++j)
    pbc[j] = make_float4(acc[6 + 2 * j], acc[22 + 2 * j],
                         acc[7 + 2 * j], acc[23 + 2 * j]);
}

// ---------------------------------------------------------------------------
// K3c: dt_proj + softplus → dt[dirb][d][l]
// ---------------------------------------------------------------------------
__global__ __launch_bounds__(256) void k3c_dt(const float* __restrict__ dbl6,
    const float* __restrict__ dtw_f, const float* __restrict__ dtb_f,
    const float* __restrict__ dtw_b, const float* __restrict__ dtb_b,
    float* __restrict__ dt) {
  const int dirb = blockIdx.y, dir = dirb >> 1;
  const int l = (blockIdx.x << 8) + threadIdx.x;
  const float* dw = dir ? dtw_b : dtw_f;
  const float* db = dir ? dtb_b : dtb_f;
  float v[6];
#pragma unroll
  for (int r = 0; r < 6; ++r) v[r] = dbl6[((size_t)dirb * 6 + r) * LSEQ + l];
  for (int d = 0; d < 192; ++d) {
    float s = db[d];
#pragma unroll
    for (int r = 0; r < 6; ++r) s = fmaf(dw[d * 6 + r], v[r], s);
    dt[((size_t)dirb * 192 + d) * LSEQ + l] = (s > 20.f) ? s : log1pf(__expf(s));
  }
}

// ---------------------------------------------------------------------------
// Scan pass A: per-chunk decay product P=exp(Adn*Σdt) and local end-state.
// dt and xc staged from global; (dt, dt*xc) packed into LDS at stage time.
// ---------------------------------------------------------------------------
template<int DIR>
__device__ __forceinline__ void scanA_body(
    float2 (*sdt)[16][34], float2 (*sbc)[TS][16],
    const float* __restrict__ dtg, const float* __restrict__ xcg,
    const float2* __restrict__ pbc, const float* __restrict__ Al,
    float* __restrict__ Pb, float* __restrict__ Hb, int b, int c, int dg) {
  const int tid = threadIdx.x;
  const int dl = tid >> 4, n = tid & 15;
  const int dirb = DIR * 2 + b;
  const int d = (dg << 4) + dl;
  const float Adn = -__expf(Al[d * 16 + n]);
  const float* dtp = dtg + ((size_t)(dirb * 192) + d) * LSEQ;
  const float* xcp = xcg + ((size_t)(dirb * 192) + d) * LSEQ;
  const int c0 = c << 8;
  const int tl2 = (tid & 15) * 2;
  const int br = tid >> 3, bcc = (tid & 7) * 2;
  {
    const int t0 = c0 + (DIR ? (NST - 1) : 0) * TS;
    const float2 a  = *(const float2*)&dtp[t0 + tl2];
    const float2 xu = *(const float2*)&xcp[t0 + tl2];
    const float4 rbc = *(const float4*)&pbc[(size_t)(t0 + br) * 16 + bcc];
    float4 pk; pk.x = a.x; pk.y = a.x * xu.x; pk.z = a.y; pk.w = a.y * xu.y;
    *(float4*)&sdt[0][dl][tl2] = pk;
    *(float4*)&sbc[0][br][bcc] = rbc;
  }
  __syncthreads();
  float h = 0.f, dts = 0.f;
  int buf = 0;
  for (int i = 0; i < NST; ++i) {
    const int s = DIR ? (NST - 1 - i) : i;
    float2 a = make_float2(0.f, 0.f), xu = make_float2(0.f, 0.f);
    float4 rbc = make_float4(0.f, 0.f, 0.f, 0.f);
    if (i + 1 < NST) {
      const int t0n = c0 + (DIR ? (s - 1) : (s + 1)) * TS;
      a   = *(const float2*)&dtp[t0n + tl2];
      xu  = *(const float2*)&xcp[t0n + tl2];
      rbc = *(const float4*)&pbc[(size_t)(t0n + br) * 16 + bcc];
    }
#pragma unroll
    for (int tt = 0; tt < TS; ++tt) {
      const int t = DIR ? (TS - 1 - tt) : tt;
      const float2 xv = sdt[buf][dl][t];
      const float Bn = sbc[buf][t][n].x;
      const float av = __expf(xv.x * Adn);
      h = fmaf(av, h, xv.y * Bn);
      dts += xv.x;
    }
    if (i + 1 < NST) {
      float4 pk; pk.x = a.x; pk.y = a.x * xu.x; pk.z = a.y; pk.w = a.y * xu.y;
      *(float4*)&sdt[buf ^ 1][dl][tl2] = pk;
      *(float4*)&sbc[buf ^ 1][br][bcc] = rbc;
    }
    __syncthreads();
    buf ^= 1;
  }
  const int o = ((dirb * 32 + c) * 192 + d) * 16 + n;
  Pb[o] = __expf(dts * Adn);
  Hb[o] = h;
}

__global__ __launch_bounds__(256) void k4_scanA(const float* __restrict__ dtg,
    const float* __restrict__ xcg, const float2* __restrict__ bc2,
    const float* __restrict__ Al_f, const float* __restrict__ Al_b,
    float* __restrict__ Pb, float* __restrict__ Hb) {
  __shared__ float2 sdt[2][16][34];
  __shared__ float2 sbc[2][TS][16];
  const int b = blockIdx.y, c = blockIdx.x & 31, dg = blockIdx.x >> 5;
  const float2* pbc0 = bc2 + (size_t)(0 * 2 + b) * LSEQ * 16;
  const float2* pbc1 = bc2 + (size_t)(1 * 2 + b) * LSEQ * 16;
  if (blockIdx.z == 0) scanA_body<0>(sdt, sbc, dtg, xcg, pbc0, Al_f, Pb, Hb, b, c, dg);
  else                 scanA_body<1>(sdt, sbc, dtg, xcg, pbc1, Al_b, Pb, Hb, b, c, dg);
}

// ---------------------------------------------------------------------------
// K5: chunk-level prefix over 32 chunks
// ---------------------------------------------------------------------------
__global__ __launch_bounds__(256) void k5_scanB(const float* __restrict__ Pb,
    const float* __restrict__ Hb, float* __restrict__ H0) {
  const int g = blockIdx.x * 256 + threadIdx.x;
  const int dirb = g / 3072, dn = g - dirb * 3072;
  const int dir = dirb >> 1;
  const int base = dirb * (32 * 3072) + dn;
  float h = 0.f;
  if (dir == 0) {
    for (int c = 0; c < 32; ++c) {
      const int o = base + c * 3072;
      H0[o] = h;
      h = fmaf(Pb[o], h, Hb[o]);
    }
  } else {
    for (int c = 31; c >= 0; --c) {
      const int o = base + c * 3072;
      H0[o] = h;
      h = fmaf(Pb[o], h, Hb[o]);
    }
  }
}

// ---------------------------------------------------------------------------
// Scan pass C: replay with correct h0; DPP reduce; y = (p + D*xc)*silu(z).
// ---------------------------------------------------------------------------
template<int DIR>
__device__ __forceinline__ void scanC_body(
    float2 (*sdt)[16][34], float2 (*sbc)[TS][16],
    const float* __restrict__ dtg, const float* __restrict__ xcg,
    const float2* __restrict__ pbc, const float* __restrict__ xz,
    const float* __restrict__ Al, const float* __restrict__ Dv_,
    const float* __restrict__ H0, float* __restrict__ yout,
    int b, int c, int dg) {
  const int tid = threadIdx.x;
  const int dl = tid >> 4, n = tid & 15;
  const int dirb = DIR * 2 + b;
  const int d = (dg << 4) + dl;
  const float Adn = -__expf(Al[d * 16 + n]);
  const float Dv = Dv_[d];
  const float* dtp = dtg + ((size_t)(dirb * 192) + d) * LSEQ;
  const float* xcp = xcg + ((size_t)(dirb * 192) + d) * LSEQ;
  const float* psp = xz + ((size_t)(b * 384) + 192 + d) * LSEQ;
  float* py = yout + ((size_t)(b * 192) + d) * LSEQ;
  const int o = ((dirb * 32 + c) * 192 + d) * 16 + n;
  const int c0 = c << 8;
  const int tl2 = (tid & 15) * 2;
  const int br = tid >> 3, bcc = (tid & 7) * 2;
  float h = H0[o];
  const int t00 = c0 + (DIR ? (NST - 1) : 0) * TS;
  {
    const float2 a  = *(const float2*)&dtp[t00 + tl2];
    const float2 xu = *(const float2*)&xcp[t00 + tl2];
    const float4 rbc = *(const float4*)&pbc[(size_t)(t00 + br) * 16 + bcc];
    float4 pk; pk.x = a.x; pk.y = a.x * xu.x; pk.z = a.y; pk.w = a.y * xu.y;
    *(float4*)&sdt[0][dl][tl2] = pk;
    *(float4*)&sbc[0][br][bcc] = rbc;
  }
  float cxa = xcp[t00 + n], cxb = xcp[t00 + 16 + n];
  float cspa = psp[t00 + n], cspb = psp[t00 + 16 + n];
  __syncthreads();
  int buf = 0;
  for (int i = 0; i < NST; ++i) {
    const int s = DIR ? (NST - 1 - i) : i;
    const int t0 = c0 + s * TS;
    float2 a = make_float2(0.f, 0.f), xu = make_float2(0.f, 0.f);
    float4 rbc = make_float4(0.f, 0.f, 0.f, 0.f);
    float nxa = 0.f, nxb = 0.f, nspa = 0.f, nspb = 0.f;
    if (i + 1 < NST) {
      const int t0n = c0 + (DIR ? (s - 1) : (s + 1)) * TS;
      a   = *(const float2*)&dtp[t0n + tl2];
      xu  = *(const float2*)&xcp[t0n + tl2];
      rbc = *(const float4*)&pbc[(size_t)(t0n + br) * 16 + bcc];
      nxa = xcp[t0n + n]; nxb = xcp[t0n + 16 + n];
      nspa = psp[t0n + n]; nspb = psp[t0n + 16 + n];
    }
    float p0 = 0.f, p1 = 0.f;
#pragma unroll
    for (int tt = 0; tt < TS; ++tt) {
      const int t = DIR ? (TS - 1 - tt) : tt;
      const float2 xv = sdt[buf][dl][t];
      const float2 v = sbc[buf][t][n];
      const float av = __expf(xv.x * Adn);
      h = fmaf(av, h, xv.y * v.x);
      float p = red16(h * v.y);
      if (t < 16) p0 = ((t & 15) == n) ? p : p0;
      else        p1 = ((t & 15) == n) ? p : p1;
    }
    py[t0 + n]      = fmaf(Dv, cxa, p0) * cspa;
    py[t0 + 16 + n] = fmaf(Dv, cxb, p1) * cspb;
    if (i + 1 < NST) {
      float4 pk; pk.x = a.x; pk.y = a.x * xu.x; pk.z = a.y; pk.w = a.y * xu.y;
      *(float4*)&sdt[buf ^ 1][dl][tl2] = pk;
      *(float4*)&sbc[buf ^ 1][br][bcc] = rbc;
      cxa = nxa; cxb = nxb; cspa = nspa; cspb = nspb;
    }
    __syncthreads();
    buf ^= 1;
  }
}

__global__ __launch_bounds__(256) void k6_scanC(const float* __restrict__ dtg,
    const float* __restrict__ xcg, const float2* __restrict__ bc2,
    const float* __restrict__ xz, const float* __restrict__ Al_f,
    const float* __restrict__ Al_b, const float* __restrict__ D_f,
    const float* __restrict__ D_b, const float* __restrict__ H0,
    float* __restrict__ yf, float* __restrict__ yb) {
  __shared__ float2 sdt[2][16][34];
  __shared__ float2 sbc[2][TS][16];
  const int b = blockIdx.y, c = blockIdx.x & 31, dg = blockIdx.x >> 5;
  const float2* pbc0 = bc2 + (size_t)(0 * 2 + b) * LSEQ * 16;
  const float2* pbc1 = bc2 + (size_t)(1 * 2 + b) * LSEQ * 16;
  if (blockIdx.z == 0)
    scanC_body<0>(sdt, sbc, dtg, xcg, pbc0, xz, Al_f, D_f, H0, yf, b, c, dg);
  else
    scanC_body<1>(sdt, sbc, dtg, xcg, pbc1, xz, Al_b, D_b, H0, yb, b, c, dg);
}

// ---------------------------------------------------------------------------
// K7: out_proj GEMM (K=192, N=96) over yf+yb, then inverse serpentine scatter.
// ---------------------------------------------------------------------------
__global__ __launch_bounds__(256) void k7_outproj(const float* __restrict__ yf,
    const float* __restrict__ yb, const float* __restrict__ W,
    float* __restrict__ out) {
  const int m0 = blockIdx.x << 6;
  const int b = m0 >> 13, l0 = m0 & (LSEQ - 1);
  __shared__ float As[32][66];
  __shared__ float Ws[96][33];
  const int tid = threadIdx.x;
  const int tx = tid & 15, ty = tid >> 4;
  const int la = tx << 2;
  float acc[6][4] = {};
  for (int kc = 0; kc < 192; kc += 32) {
    for (int idx = tid; idx < 32 * 64; idx += 256) {
      const int k = idx >> 6, l = idx & 63;
      const size_t off = ((size_t)b * 192 + kc + k) * LSEQ + l0 + l;
      As[k][l] = yf[off] + yb[off];
    }
    for (int idx = tid; idx < 96 * 32; idx += 256) {
      const int e = idx >> 5, k = idx & 31;
      Ws[e][k] = W[e * 192 + kc + k];
    }
    __syncthreads();
#pragma unroll
    for (int k = 0; k < 32; ++k) {
      const float a0 = As[k][la], a1 = As[k][la + 1], a2 = As[k][la + 2], a3 = As[k][la + 3];
#pragma unroll
      for (int j = 0; j < 6; ++j) {
        const float w = Ws[ty * 6 + j][k];
        acc[j][0] = fmaf(w, a0, acc[j][0]);
        acc[j][1] = fmaf(w, a1, acc[j][1]);
        acc[j][2] = fmaf(w, a2, acc[j][2]);
        acc[j][3] = fmaf(w, a3, acc[j][3]);
      }
    }
    __syncthreads();
  }
#pragma unroll
  for (int j = 0; j < 6; ++j) {
    const int e = ty * 6 + j;
#pragma unroll
    for (int i = 0; i < 4; ++i) {
      const int l = l0 + la + i;
      const int hh = (l >> 5) & 31, w = l & 31;
      const int lp = (hh & 1) ? (l + 31 - 2 * w) : l;
      out[((size_t)b * 96 + e) * LSEQ + lp] = acc[j][i];
    }
  }
}

// ---------------------------------------------------------------------------
extern "C" void kernel_launch(void* const* d_in, const int* in_sizes, int n_in,
                              void* d_out, int out_size, void* d_ws, size_t ws_size,
                              hipStream_t stream) {
  const float* x     = (const float*)d_in[0];
  const float* ln_g  = (const float*)d_in[1];
  const float* ln_b  = (const float*)d_in[2];
  const float* in_w  = (const float*)d_in[3];
  const float* cw_f  = (const float*)d_in[4];
  const float* cb_f  = (const float*)d_in[5];
  const float* xw_f  = (const float*)d_in[6];
  const float* dtw_f = (const float*)d_in[7];
  const float* dtb_f = (const float*)d_in[8];
  const float* Al_f  = (const float*)d_in[9];
  const float* D_f   = (const float*)d_in[10];
  const float* cw_b  = (const float*)d_in[11];
  const float* cb_b  = (const float*)d_in[12];
  const float* xw_b  = (const float*)d_in[13];
  const float* dtw_b = (const float*)d_in[14];
  const float* dtb_b = (const float*)d_in[15];
  const float* Al_b  = (const float*)d_in[16];
  const float* D_b   = (const float*)d_in[17];
  const float* ow    = (const float*)d_in[18];
  float* out = (float*)d_out;

  float* ws = (float*)d_ws;
  float* xn   = ws; ws += (size_t)16384 * 96;           // 1.57M
  float* xz   = ws; ws += (size_t)2 * 384 * LSEQ;       // 6.29M
  float* xc   = ws; ws += (size_t)4 * 192 * LSEQ;       // 6.29M
  float* dt   = ws; ws += (size_t)4 * 192 * LSEQ;       // 6.29M
  float* BC   = ws; ws += (size_t)4 * LSEQ * 32;        // 1.05M
  float* dbl6 = ws; ws += (size_t)4 * 6 * LSEQ;         // 0.20M
  float* yf   = ws; ws += (size_t)2 * 192 * LSEQ;       // 3.15M
  float* yb   = ws; ws += (size_t)2 * 192 * LSEQ;       // 3.15M
  float* Pb   = ws; ws += (size_t)4 * 32 * 192 * 16;    // 0.39M
  float* Hb   = ws; ws += (size_t)4 * 32 * 192 * 16;    // 0.39M
  float* H0   = ws; ws += (size_t)4 * 32 * 192 * 16;    // 0.39M
  float* xwT  = ws; ws += (size_t)2 * 192 * 40;         // 15K
  // total ~28.9M floats = ~116 MB

  k0_wt<<<dim3(1), dim3(256), 0, stream>>>(xw_f, xw_b, xwT);
  k1_serp_ln<<<dim3(256), dim3(256), 0, stream>>>(x, ln_g, ln_b, xn);
  k2_inproj<<<dim3(256, 6), dim3(256), 0, stream>>>(xn, in_w, xz);
  k3a_conv<<<dim3(32, 192, 2), dim3(256), 0, stream>>>(xz, cw_f, cb_f, cw_b, cb_b, xc);
  k3b_xproj<<<dim3(64, 4), dim3(128), 0, stream>>>(xc, xwT, dbl6, BC);
  k3c_dt<<<dim3(32, 4), dim3(256), 0, stream>>>(dbl6, dtw_f, dtb_f, dtw_b, dtb_b, dt);
  k4_scanA<<<dim3(384, 2, 2), dim3(256), 0, stream>>>(dt, xc, (const float2*)BC,
      Al_f, Al_b, Pb, Hb);
  k5_scanB<<<dim3(48), dim3(256), 0, stream>>>(Pb, Hb, H0);
  k6_scanC<<<dim3(384, 2, 2), dim3(256), 0, stream>>>(dt, xc, (const float2*)BC,
      xz, Al_f, Al_b, D_f, D_b, H0, yf, yb);
  k7_outproj<<<dim3(256), dim3(256), 0, stream>>>(yf, yb, ow, out);
}

// Round 4
// 269.527 us; speedup vs baseline: 1.2245x; 1.2245x over previous
//
#include <hip/hip_runtime.h>
#include <math.h>

#define LSEQ 8192
#define TS   32
#define NST  8

// ---------------------------------------------------------------------------
// DPP 16-lane reduction. xor1=quad_perm 0xB1, xor2=0x4E, row_ror:8, row_ror:4.
// ---------------------------------------------------------------------------
template<int CTRL>
__device__ __forceinline__ float dpp_add(float x) {
  const int y = __builtin_amdgcn_update_dpp(0, __float_as_int(x), CTRL, 0xF, 0xF, true);
  return x + __int_as_float(y);
}
__device__ __forceinline__ float red16(float x) {
  x = dpp_add<0xB1>(x);
  x = dpp_add<0x4E>(x);
  x = dpp_add<0x128>(x);
  x = dpp_add<0x124>(x);
  return x;
}

// ---------------------------------------------------------------------------
// K0: transpose x_proj weights to [dir][k=192][40] (r-minor, padded) for s_load
// ---------------------------------------------------------------------------
__global__ __launch_bounds__(256) void k0_wt(const float* __restrict__ xw_f,
    const float* __restrict__ xw_b, float* __restrict__ xwT) {
  for (int idx = threadIdx.x; idx < 2 * 192 * 40; idx += 256) {
    const int dir = idx / (192 * 40), rem = idx - dir * 192 * 40;
    const int k = rem / 40, r = rem - k * 40;
    const float* w = dir ? xw_b : xw_f;
    xwT[idx] = (r < 38) ? w[r * 192 + k] : 0.f;
  }
}

// ---------------------------------------------------------------------------
// K1: serpentine gather + LayerNorm over C=96.  out: xn[(b*L+l)*96 + c]
// ---------------------------------------------------------------------------
__global__ __launch_bounds__(256) void k1_serp_ln(const float* __restrict__ x,
    const float* __restrict__ gam, const float* __restrict__ bet,
    float* __restrict__ xn) {
  const int b  = blockIdx.x >> 7;
  const int l0 = (blockIdx.x & 127) << 6;
  __shared__ float xs[96][65];
  __shared__ float mu[64], rs[64];
  const int tid = threadIdx.x;
  for (int idx = tid; idx < 96 * 64; idx += 256) {
    const int c = idx >> 6, l = idx & 63;
    const int lg = l0 + l;
    const int hh = (lg >> 5) & 31, w = lg & 31;
    const int lsrc = (hh & 1) ? (lg + 31 - 2 * w) : lg;
    xs[c][l] = x[(b * 96 + c) * LSEQ + lsrc];
  }
  __syncthreads();
  {
    const int l = tid >> 2, k = tid & 3;
    float s = 0.f, s2 = 0.f;
    for (int c = k; c < 96; c += 4) { const float v = xs[c][l]; s += v; s2 += v * v; }
    s  += __shfl_xor(s, 1);  s  += __shfl_xor(s, 2);
    s2 += __shfl_xor(s2, 1); s2 += __shfl_xor(s2, 2);
    if (k == 0) {
      const float m = s * (1.f / 96.f);
      const float var = s2 * (1.f / 96.f) - m * m;
      mu[l] = m; rs[l] = rsqrtf(var + 1e-5f);
    }
  }
  __syncthreads();
  for (int idx = tid; idx < 64 * 96; idx += 256) {
    const int l = idx / 96, c = idx - l * 96;
    xn[((size_t)b * LSEQ + l0) * 96 + idx] = (xs[c][l] - mu[l]) * rs[l] * gam[c] + bet[c];
  }
}

// ---------------------------------------------------------------------------
// K2: in_proj GEMM  M=16384 x N=384, K=96.  Writes transposed xz[b][e][l];
//     silu applied for e>=192 (the z half).
// ---------------------------------------------------------------------------
__global__ __launch_bounds__(256) void k2_inproj(const float* __restrict__ xn,
    const float* __restrict__ W, float* __restrict__ xz) {
  const int m0 = blockIdx.x << 6;
  const int e0 = blockIdx.y << 6;
  __shared__ float As[96][67];
  __shared__ float Ws[96][67];
  const int tid = threadIdx.x;
  for (int idx = tid; idx < 64 * 96; idx += 256) {
    const int r = idx / 96, k = idx - r * 96;
    As[k][r] = xn[(size_t)m0 * 96 + idx];
    Ws[k][r] = W[(size_t)e0 * 96 + idx];
  }
  __syncthreads();
  const int tx = tid & 15, ty = tid >> 4;
  const int la = tx << 2, ea = ty << 2;
  float acc[4][4] = {};
  for (int k = 0; k < 96; ++k) {
    float av[4], bv[4];
#pragma unroll
    for (int i = 0; i < 4; ++i) av[i] = As[k][la + i];
#pragma unroll
    for (int j = 0; j < 4; ++j) bv[j] = Ws[k][ea + j];
#pragma unroll
    for (int j = 0; j < 4; ++j)
#pragma unroll
      for (int i = 0; i < 4; ++i) acc[j][i] = fmaf(bv[j], av[i], acc[j][i]);
  }
  const int b = m0 >> 13, l0 = m0 & (LSEQ - 1);
  const bool dos = (e0 >= 192);
#pragma unroll
  for (int j = 0; j < 4; ++j) {
    const int e = e0 + ea + j;
    float4 v;
    v.x = acc[j][0]; v.y = acc[j][1]; v.z = acc[j][2]; v.w = acc[j][3];
    if (dos) {
      v.x = v.x / (1.f + __expf(-v.x)); v.y = v.y / (1.f + __expf(-v.y));
      v.z = v.z / (1.f + __expf(-v.z)); v.w = v.w / (1.f + __expf(-v.w));
    }
    *(float4*)(&xz[((size_t)b * 384 + e) * LSEQ + l0 + la]) = v;
  }
}

// ---------------------------------------------------------------------------
// K3a: depthwise conv + silu for BOTH directions (shared xz read).
//      xc[dirb][d][l], dirb = dir*2 + b.
// ---------------------------------------------------------------------------
__global__ __launch_bounds__(256) void k3a_conv(const float* __restrict__ xz,
    const float* __restrict__ cw_f, const float* __restrict__ cb_f,
    const float* __restrict__ cw_b, const float* __restrict__ cb_b,
    float* __restrict__ xc) {
  const int l = (blockIdx.x << 8) + threadIdx.x;
  const int d = blockIdx.y, b = blockIdx.z;
  const float* xin = xz + ((size_t)b * 384 + d) * LSEQ;
  float xv[7];
#pragma unroll
  for (int j = -3; j <= 3; ++j) {
    const int ls = l + j;
    xv[j + 3] = ((unsigned)ls < LSEQ) ? xin[ls] : 0.f;
  }
  float af = cb_f[d], ab = cb_b[d];
#pragma unroll
  for (int j = 0; j < 4; ++j) {
    af = fmaf(cw_f[d * 4 + j], xv[j], af);       // x[l-3+j]
    ab = fmaf(cw_b[d * 4 + j], xv[6 - j], ab);   // x[l+3-j]
  }
  xc[((size_t)(b)       * 192 + d) * LSEQ + l] = af / (1.f + __expf(-af));
  xc[((size_t)(2 + b)   * 192 + d) * LSEQ + l] = ab / (1.f + __expf(-ab));
}

// ---------------------------------------------------------------------------
// K3b: x_proj + dt_proj + softplus, fused.  One wave per block (grid spreads
// over all CUs); weights via wave-uniform scalar loads; 38 VGPR accumulators.
// Writes BC interleaved + dt.
// ---------------------------------------------------------------------------
__global__ __launch_bounds__(64) void k3b_xproj(const float* __restrict__ xc,
    const float* __restrict__ xwT,
    const float* __restrict__ dtw_f, const float* __restrict__ dtb_f,
    const float* __restrict__ dtw_b, const float* __restrict__ dtb_b,
    float* __restrict__ dt, float* __restrict__ BCo) {
  const int dirb = blockIdx.y, dir = dirb >> 1;
  const int l = (blockIdx.x << 6) + threadIdx.x;
  const float* pc = xc + (size_t)dirb * 192 * LSEQ + l;
  const float* w = xwT + dir * 192 * 40;
  float acc[38];
#pragma unroll
  for (int r = 0; r < 38; ++r) acc[r] = 0.f;
#pragma unroll 4
  for (int k = 0; k < 192; ++k) {
    const float v = pc[(size_t)k * LSEQ];
    const float* wk = w + k * 40;
#pragma unroll
    for (int r = 0; r < 38; ++r) acc[r] = fmaf(wk[r], v, acc[r]);
  }
  // B/C interleaved: per lane a contiguous 128B segment.
  float4* pbc = (float4*)(BCo + ((size_t)dirb * LSEQ + l) * 32);
#pragma unroll
  for (int j = 0; j < 8; ++j)
    pbc[j] = make_float4(acc[6 + 2 * j], acc[22 + 2 * j],
                         acc[7 + 2 * j], acc[23 + 2 * j]);
  // dt_proj + softplus (native exp/log; guard covers overflow, underflow ok)
  const float* dw = dir ? dtw_b : dtw_f;
  const float* db = dir ? dtb_b : dtb_f;
  float* pdt = dt + (size_t)dirb * 192 * LSEQ + l;
#pragma unroll 4
  for (int d = 0; d < 192; ++d) {
    float s = db[d];
#pragma unroll
    for (int r = 0; r < 6; ++r) s = fmaf(dw[d * 6 + r], acc[r], s);
    pdt[(size_t)d * LSEQ] = (s > 20.f) ? s : __logf(1.f + __expf(s));
  }
}

// ---------------------------------------------------------------------------
// Scan pass A: per-chunk decay product P=exp(Adn*Σdt) and local end-state.
// dt and xc staged from global; (dt, dt*xc) packed into LDS at stage time.
// ---------------------------------------------------------------------------
template<int DIR>
__device__ __forceinline__ void scanA_body(
    float2 (*sdt)[16][34], float2 (*sbc)[TS][16],
    const float* __restrict__ dtg, const float* __restrict__ xcg,
    const float2* __restrict__ pbc, const float* __restrict__ Al,
    float* __restrict__ Pb, float* __restrict__ Hb, int b, int c, int dg) {
  const int tid = threadIdx.x;
  const int dl = tid >> 4, n = tid & 15;
  const int dirb = DIR * 2 + b;
  const int d = (dg << 4) + dl;
  const float Adn = -__expf(Al[d * 16 + n]);
  const float* dtp = dtg + ((size_t)(dirb * 192) + d) * LSEQ;
  const float* xcp = xcg + ((size_t)(dirb * 192) + d) * LSEQ;
  const int c0 = c << 8;
  const int tl2 = (tid & 15) * 2;
  const int br = tid >> 3, bcc = (tid & 7) * 2;
  {
    const int t0 = c0 + (DIR ? (NST - 1) : 0) * TS;
    const float2 a  = *(const float2*)&dtp[t0 + tl2];
    const float2 xu = *(const float2*)&xcp[t0 + tl2];
    const float4 rbc = *(const float4*)&pbc[(size_t)(t0 + br) * 16 + bcc];
    float4 pk; pk.x = a.x; pk.y = a.x * xu.x; pk.z = a.y; pk.w = a.y * xu.y;
    *(float4*)&sdt[0][dl][tl2] = pk;
    *(float4*)&sbc[0][br][bcc] = rbc;
  }
  __syncthreads();
  float h = 0.f, dts = 0.f;
  int buf = 0;
  for (int i = 0; i < NST; ++i) {
    const int s = DIR ? (NST - 1 - i) : i;
    float2 a = make_float2(0.f, 0.f), xu = make_float2(0.f, 0.f);
    float4 rbc = make_float4(0.f, 0.f, 0.f, 0.f);
    if (i + 1 < NST) {
      const int t0n = c0 + (DIR ? (s - 1) : (s + 1)) * TS;
      a   = *(const float2*)&dtp[t0n + tl2];
      xu  = *(const float2*)&xcp[t0n + tl2];
      rbc = *(const float4*)&pbc[(size_t)(t0n + br) * 16 + bcc];
    }
#pragma unroll
    for (int tt = 0; tt < TS; ++tt) {
      const int t = DIR ? (TS - 1 - tt) : tt;
      const float2 xv = sdt[buf][dl][t];
      const float Bn = sbc[buf][t][n].x;
      const float av = __expf(xv.x * Adn);
      h = fmaf(av, h, xv.y * Bn);
      dts += xv.x;
    }
    if (i + 1 < NST) {
      float4 pk; pk.x = a.x; pk.y = a.x * xu.x; pk.z = a.y; pk.w = a.y * xu.y;
      *(float4*)&sdt[buf ^ 1][dl][tl2] = pk;
      *(float4*)&sbc[buf ^ 1][br][bcc] = rbc;
    }
    __syncthreads();
    buf ^= 1;
  }
  const int o = ((dirb * 32 + c) * 192 + d) * 16 + n;
  Pb[o] = __expf(dts * Adn);
  Hb[o] = h;
}

__global__ __launch_bounds__(256) void k4_scanA(const float* __restrict__ dtg,
    const float* __restrict__ xcg, const float2* __restrict__ bc2,
    const float* __restrict__ Al_f, const float* __restrict__ Al_b,
    float* __restrict__ Pb, float* __restrict__ Hb) {
  __shared__ float2 sdt[2][16][34];
  __shared__ float2 sbc[2][TS][16];
  const int b = blockIdx.y, c = blockIdx.x & 31, dg = blockIdx.x >> 5;
  const float2* pbc0 = bc2 + (size_t)(0 * 2 + b) * LSEQ * 16;
  const float2* pbc1 = bc2 + (size_t)(1 * 2 + b) * LSEQ * 16;
  if (blockIdx.z == 0) scanA_body<0>(sdt, sbc, dtg, xcg, pbc0, Al_f, Pb, Hb, b, c, dg);
  else                 scanA_body<1>(sdt, sbc, dtg, xcg, pbc1, Al_b, Pb, Hb, b, c, dg);
}

// ---------------------------------------------------------------------------
// K5: chunk-level prefix over 32 chunks
// ---------------------------------------------------------------------------
__global__ __launch_bounds__(256) void k5_scanB(const float* __restrict__ Pb,
    const float* __restrict__ Hb, float* __restrict__ H0) {
  const int g = blockIdx.x * 256 + threadIdx.x;
  const int dirb = g / 3072, dn = g - dirb * 3072;
  const int dir = dirb >> 1;
  const int base = dirb * (32 * 3072) + dn;
  float h = 0.f;
  if (dir == 0) {
    for (int c = 0; c < 32; ++c) {
      const int o = base + c * 3072;
      H0[o] = h;
      h = fmaf(Pb[o], h, Hb[o]);
    }
  } else {
    for (int c = 31; c >= 0; --c) {
      const int o = base + c * 3072;
      H0[o] = h;
      h = fmaf(Pb[o], h, Hb[o]);
    }
  }
}

// ---------------------------------------------------------------------------
// Scan pass C: replay with correct h0; DPP reduce; y = (p + D*xc)*silu(z).
// ---------------------------------------------------------------------------
template<int DIR>
__device__ __forceinline__ void scanC_body(
    float2 (*sdt)[16][34], float2 (*sbc)[TS][16],
    const float* __restrict__ dtg, const float* __restrict__ xcg,
    const float2* __restrict__ pbc, const float* __restrict__ xz,
    const float* __restrict__ Al, const float* __restrict__ Dv_,
    const float* __restrict__ H0, float* __restrict__ yout,
    int b, int c, int dg) {
  const int tid = threadIdx.x;
  const int dl = tid >> 4, n = tid & 15;
  const int dirb = DIR * 2 + b;
  const int d = (dg << 4) + dl;
  const float Adn = -__expf(Al[d * 16 + n]);
  const float Dv = Dv_[d];
  const float* dtp = dtg + ((size_t)(dirb * 192) + d) * LSEQ;
  const float* xcp = xcg + ((size_t)(dirb * 192) + d) * LSEQ;
  const float* psp = xz + ((size_t)(b * 384) + 192 + d) * LSEQ;
  float* py = yout + ((size_t)(b * 192) + d) * LSEQ;
  const int o = ((dirb * 32 + c) * 192 + d) * 16 + n;
  const int c0 = c << 8;
  const int tl2 = (tid & 15) * 2;
  const int br = tid >> 3, bcc = (tid & 7) * 2;
  float h = H0[o];
  const int t00 = c0 + (DIR ? (NST - 1) : 0) * TS;
  {
    const float2 a  = *(const float2*)&dtp[t00 + tl2];
    const float2 xu = *(const float2*)&xcp[t00 + tl2];
    const float4 rbc = *(const float4*)&pbc[(size_t)(t00 + br) * 16 + bcc];
    float4 pk; pk.x = a.x; pk.y = a.x * xu.x; pk.z = a.y; pk.w = a.y * xu.y;
    *(float4*)&sdt[0][dl][tl2] = pk;
    *(float4*)&sbc[0][br][bcc] = rbc;
  }
  float cxa = xcp[t00 + n], cxb = xcp[t00 + 16 + n];
  float cspa = psp[t00 + n], cspb = psp[t00 + 16 + n];
  __syncthreads();
  int buf = 0;
  for (int i = 0; i < NST; ++i) {
    const int s = DIR ? (NST - 1 - i) : i;
    const int t0 = c0 + s * TS;
    float2 a = make_float2(0.f, 0.f), xu = make_float2(0.f, 0.f);
    float4 rbc = make_float4(0.f, 0.f, 0.f, 0.f);
    float nxa = 0.f, nxb = 0.f, nspa = 0.f, nspb = 0.f;
    if (i + 1 < NST) {
      const int t0n = c0 + (DIR ? (s - 1) : (s + 1)) * TS;
      a   = *(const float2*)&dtp[t0n + tl2];
      xu  = *(const float2*)&xcp[t0n + tl2];
      rbc = *(const float4*)&pbc[(size_t)(t0n + br) * 16 + bcc];
      nxa = xcp[t0n + n]; nxb = xcp[t0n + 16 + n];
      nspa = psp[t0n + n]; nspb = psp[t0n + 16 + n];
    }
    float p0 = 0.f, p1 = 0.f;
#pragma unroll
    for (int tt = 0; tt < TS; ++tt) {
      const int t = DIR ? (TS - 1 - tt) : tt;
      const float2 xv = sdt[buf][dl][t];
      const float2 v = sbc[buf][t][n];
      const float av = __expf(xv.x * Adn);
      h = fmaf(av, h, xv.y * v.x);
      float p = red16(h * v.y);
      if (t < 16) p0 = ((t & 15) == n) ? p : p0;
      else        p1 = ((t & 15) == n) ? p : p1;
    }
    py[t0 + n]      = fmaf(Dv, cxa, p0) * cspa;
    py[t0 + 16 + n] = fmaf(Dv, cxb, p1) * cspb;
    if (i + 1 < NST) {
      float4 pk; pk.x = a.x; pk.y = a.x * xu.x; pk.z = a.y; pk.w = a.y * xu.y;
      *(float4*)&sdt[buf ^ 1][dl][tl2] = pk;
      *(float4*)&sbc[buf ^ 1][br][bcc] = rbc;
      cxa = nxa; cxb = nxb; cspa = nspa; cspb = nspb;
    }
    __syncthreads();
    buf ^= 1;
  }
}

__global__ __launch_bounds__(256) void k6_scanC(const float* __restrict__ dtg,
    const float* __restrict__ xcg, const float2* __restrict__ bc2,
    const float* __restrict__ xz, const float* __restrict__ Al_f,
    const float* __restrict__ Al_b, const float* __restrict__ D_f,
    const float* __restrict__ D_b, const float* __restrict__ H0,
    float* __restrict__ yf, float* __restrict__ yb) {
  __shared__ float2 sdt[2][16][34];
  __shared__ float2 sbc[2][TS][16];
  const int b = blockIdx.y, c = blockIdx.x & 31, dg = blockIdx.x >> 5;
  const float2* pbc0 = bc2 + (size_t)(0 * 2 + b) * LSEQ * 16;
  const float2* pbc1 = bc2 + (size_t)(1 * 2 + b) * LSEQ * 16;
  if (blockIdx.z == 0)
    scanC_body<0>(sdt, sbc, dtg, xcg, pbc0, xz, Al_f, D_f, H0, yf, b, c, dg);
  else
    scanC_body<1>(sdt, sbc, dtg, xcg, pbc1, xz, Al_b, D_b, H0, yb, b, c, dg);
}

// ---------------------------------------------------------------------------
// K7: out_proj GEMM (K=192, N=96) over yf+yb, then inverse serpentine scatter.
// ---------------------------------------------------------------------------
__global__ __launch_bounds__(256) void k7_outproj(const float* __restrict__ yf,
    const float* __restrict__ yb, const float* __restrict__ W,
    float* __restrict__ out) {
  const int m0 = blockIdx.x << 6;
  const int b = m0 >> 13, l0 = m0 & (LSEQ - 1);
  __shared__ float As[32][66];
  __shared__ float Ws[96][33];
  const int tid = threadIdx.x;
  const int tx = tid & 15, ty = tid >> 4;
  const int la = tx << 2;
  float acc[6][4] = {};
  for (int kc = 0; kc < 192; kc += 32) {
    for (int idx = tid; idx < 32 * 64; idx += 256) {
      const int k = idx >> 6, l = idx & 63;
      const size_t off = ((size_t)b * 192 + kc + k) * LSEQ + l0 + l;
      As[k][l] = yf[off] + yb[off];
    }
    for (int idx = tid; idx < 96 * 32; idx += 256) {
      const int e = idx >> 5, k = idx & 31;
      Ws[e][k] = W[e * 192 + kc + k];
    }
    __syncthreads();
#pragma unroll
    for (int k = 0; k < 32; ++k) {
      const float a0 = As[k][la], a1 = As[k][la + 1], a2 = As[k][la + 2], a3 = As[k][la + 3];
#pragma unroll
      for (int j = 0; j < 6; ++j) {
        const float w = Ws[ty * 6 + j][k];
        acc[j][0] = fmaf(w, a0, acc[j][0]);
        acc[j][1] = fmaf(w, a1, acc[j][1]);
        acc[j][2] = fmaf(w, a2, acc[j][2]);
        acc[j][3] = fmaf(w, a3, acc[j][3]);
      }
    }
    __syncthreads();
  }
#pragma unroll
  for (int j = 0; j < 6; ++j) {
    const int e = ty * 6 + j;
#pragma unroll
    for (int i = 0; i < 4; ++i) {
      const int l = l0 + la + i;
      const int hh = (l >> 5) & 31, w = l & 31;
      const int lp = (hh & 1) ? (l + 31 - 2 * w) : l;
      out[((size_t)b * 96 + e) * LSEQ + lp] = acc[j][i];
    }
  }
}

// ---------------------------------------------------------------------------
extern "C" void kernel_launch(void* const* d_in, const int* in_sizes, int n_in,
                              void* d_out, int out_size, void* d_ws, size_t ws_size,
                              hipStream_t stream) {
  const float* x     = (const float*)d_in[0];
  const float* ln_g  = (const float*)d_in[1];
  const float* ln_b  = (const float*)d_in[2];
  const float* in_w  = (const float*)d_in[3];
  const float* cw_f  = (const float*)d_in[4];
  const float* cb_f  = (const float*)d_in[5];
  const float* xw_f  = (const float*)d_in[6];
  const float* dtw_f = (const float*)d_in[7];
  const float* dtb_f = (const float*)d_in[8];
  const float* Al_f  = (const float*)d_in[9];
  const float* D_f   = (const float*)d_in[10];
  const float* cw_b  = (const float*)d_in[11];
  const float* cb_b  = (const float*)d_in[12];
  const float* xw_b  = (const float*)d_in[13];
  const float* dtw_b = (const float*)d_in[14];
  const float* dtb_b = (const float*)d_in[15];
  const float* Al_b  = (const float*)d_in[16];
  const float* D_b   = (const float*)d_in[17];
  const float* ow    = (const float*)d_in[18];
  float* out = (float*)d_out;

  float* ws = (float*)d_ws;
  float* xn   = ws; ws += (size_t)16384 * 96;           // 1.57M
  float* xz   = ws; ws += (size_t)2 * 384 * LSEQ;       // 6.29M
  float* xc   = ws; ws += (size_t)4 * 192 * LSEQ;       // 6.29M
  float* dt   = ws; ws += (size_t)4 * 192 * LSEQ;       // 6.29M
  float* BC   = ws; ws += (size_t)4 * LSEQ * 32;        // 1.05M
  float* yf   = ws; ws += (size_t)2 * 192 * LSEQ;       // 3.15M
  float* yb   = ws; ws += (size_t)2 * 192 * LSEQ;       // 3.15M
  float* Pb   = ws; ws += (size_t)4 * 32 * 192 * 16;    // 0.39M
  float* Hb   = ws; ws += (size_t)4 * 32 * 192 * 16;    // 0.39M
  float* H0   = ws; ws += (size_t)4 * 32 * 192 * 16;    // 0.39M
  float* xwT  = ws; ws += (size_t)2 * 192 * 40;         // 15K

  k0_wt<<<dim3(1), dim3(256), 0, stream>>>(xw_f, xw_b, xwT);
  k1_serp_ln<<<dim3(256), dim3(256), 0, stream>>>(x, ln_g, ln_b, xn);
  k2_inproj<<<dim3(256, 6), dim3(256), 0, stream>>>(xn, in_w, xz);
  k3a_conv<<<dim3(32, 192, 2), dim3(256), 0, stream>>>(xz, cw_f, cb_f, cw_b, cb_b, xc);
  k3b_xproj<<<dim3(128, 4), dim3(64), 0, stream>>>(xc, xwT,
      dtw_f, dtb_f, dtw_b, dtb_b, dt, BC);
  k4_scanA<<<dim3(384, 2, 2), dim3(256), 0, stream>>>(dt, xc, (const float2*)BC,
      Al_f, Al_b, Pb, Hb);
  k5_scanB<<<dim3(48), dim3(256), 0, stream>>>(Pb, Hb, H0);
  k6_scanC<<<dim3(384, 2, 2), dim3(256), 0, stream>>>(dt, xc, (const float2*)BC,
      xz, Al_f, Al_b, D_f, D_b, H0, yf, yb);
  k7_outproj<<<dim3(256), dim3(256), 0, stream>>>(yf, yb, ow, out);
}

// Round 5
// 223.710 us; speedup vs baseline: 1.4753x; 1.2048x over previous
//
#include <hip/hip_runtime.h>
#include <math.h>

#define LSEQ 8192
#define TS   32
#define NST  8

// ---------------------------------------------------------------------------
// DPP 16-lane reduction. xor1=quad_perm 0xB1, xor2=0x4E, row_ror:8, row_ror:4.
// ---------------------------------------------------------------------------
template<int CTRL>
__device__ __forceinline__ float dpp_add(float x) {
  const int y = __builtin_amdgcn_update_dpp(0, __float_as_int(x), CTRL, 0xF, 0xF, true);
  return x + __int_as_float(y);
}
__device__ __forceinline__ float red16(float x) {
  x = dpp_add<0xB1>(x);
  x = dpp_add<0x4E>(x);
  x = dpp_add<0x128>(x);
  x = dpp_add<0x124>(x);
  return x;
}

// ---------------------------------------------------------------------------
// K0: transpose x_proj weights to [dir][k=192][40] (r-minor, padded) for s_load
// ---------------------------------------------------------------------------
__global__ __launch_bounds__(256) void k0_wt(const float* __restrict__ xw_f,
    const float* __restrict__ xw_b, float* __restrict__ xwT) {
  for (int idx = threadIdx.x; idx < 2 * 192 * 40; idx += 256) {
    const int dir = idx / (192 * 40), rem = idx - dir * 192 * 40;
    const int k = rem / 40, r = rem - k * 40;
    const float* w = dir ? xw_b : xw_f;
    xwT[idx] = (r < 38) ? w[r * 192 + k] : 0.f;
  }
}

// ---------------------------------------------------------------------------
// K1: serpentine gather + LayerNorm over C=96.  out: xn[(b*L+l)*96 + c]
// ---------------------------------------------------------------------------
__global__ __launch_bounds__(256) void k1_serp_ln(const float* __restrict__ x,
    const float* __restrict__ gam, const float* __restrict__ bet,
    float* __restrict__ xn) {
  const int b  = blockIdx.x >> 7;
  const int l0 = (blockIdx.x & 127) << 6;
  __shared__ float xs[96][65];
  __shared__ float mu[64], rs[64];
  const int tid = threadIdx.x;
  for (int idx = tid; idx < 96 * 64; idx += 256) {
    const int c = idx >> 6, l = idx & 63;
    const int lg = l0 + l;
    const int hh = (lg >> 5) & 31, w = lg & 31;
    const int lsrc = (hh & 1) ? (lg + 31 - 2 * w) : lg;
    xs[c][l] = x[(b * 96 + c) * LSEQ + lsrc];
  }
  __syncthreads();
  {
    const int l = tid >> 2, k = tid & 3;
    float s = 0.f, s2 = 0.f;
    for (int c = k; c < 96; c += 4) { const float v = xs[c][l]; s += v; s2 += v * v; }
    s  += __shfl_xor(s, 1);  s  += __shfl_xor(s, 2);
    s2 += __shfl_xor(s2, 1); s2 += __shfl_xor(s2, 2);
    if (k == 0) {
      const float m = s * (1.f / 96.f);
      const float var = s2 * (1.f / 96.f) - m * m;
      mu[l] = m; rs[l] = rsqrtf(var + 1e-5f);
    }
  }
  __syncthreads();
  for (int idx = tid; idx < 64 * 96; idx += 256) {
    const int l = idx / 96, c = idx - l * 96;
    xn[((size_t)b * LSEQ + l0) * 96 + idx] = (xs[c][l] - mu[l]) * rs[l] * gam[c] + bet[c];
  }
}

// ---------------------------------------------------------------------------
// K2: in_proj GEMM  M=16384 x N=384, K=96.  Writes transposed xz[b][e][l];
//     silu applied for e>=192 (the z half).
// ---------------------------------------------------------------------------
__global__ __launch_bounds__(256) void k2_inproj(const float* __restrict__ xn,
    const float* __restrict__ W, float* __restrict__ xz) {
  const int m0 = blockIdx.x << 6;
  const int e0 = blockIdx.y << 6;
  __shared__ float As[96][67];
  __shared__ float Ws[96][67];
  const int tid = threadIdx.x;
  for (int idx = tid; idx < 64 * 96; idx += 256) {
    const int r = idx / 96, k = idx - r * 96;
    As[k][r] = xn[(size_t)m0 * 96 + idx];
    Ws[k][r] = W[(size_t)e0 * 96 + idx];
  }
  __syncthreads();
  const int tx = tid & 15, ty = tid >> 4;
  const int la = tx << 2, ea = ty << 2;
  float acc[4][4] = {};
  for (int k = 0; k < 96; ++k) {
    float av[4], bv[4];
#pragma unroll
    for (int i = 0; i < 4; ++i) av[i] = As[k][la + i];
#pragma unroll
    for (int j = 0; j < 4; ++j) bv[j] = Ws[k][ea + j];
#pragma unroll
    for (int j = 0; j < 4; ++j)
#pragma unroll
      for (int i = 0; i < 4; ++i) acc[j][i] = fmaf(bv[j], av[i], acc[j][i]);
  }
  const int b = m0 >> 13, l0 = m0 & (LSEQ - 1);
  const bool dos = (e0 >= 192);
#pragma unroll
  for (int j = 0; j < 4; ++j) {
    const int e = e0 + ea + j;
    float4 v;
    v.x = acc[j][0]; v.y = acc[j][1]; v.z = acc[j][2]; v.w = acc[j][3];
    if (dos) {
      v.x = v.x / (1.f + __expf(-v.x)); v.y = v.y / (1.f + __expf(-v.y));
      v.z = v.z / (1.f + __expf(-v.z)); v.w = v.w / (1.f + __expf(-v.w));
    }
    *(float4*)(&xz[((size_t)b * 384 + e) * LSEQ + l0 + la]) = v;
  }
}

// ---------------------------------------------------------------------------
// K3a: depthwise conv + silu for BOTH directions (shared xz read).
//      xc[dirb][d][l], dirb = dir*2 + b.
// ---------------------------------------------------------------------------
__global__ __launch_bounds__(256) void k3a_conv(const float* __restrict__ xz,
    const float* __restrict__ cw_f, const float* __restrict__ cb_f,
    const float* __restrict__ cw_b, const float* __restrict__ cb_b,
    float* __restrict__ xc) {
  const int l = (blockIdx.x << 8) + threadIdx.x;
  const int d = blockIdx.y, b = blockIdx.z;
  const float* xin = xz + ((size_t)b * 384 + d) * LSEQ;
  float xv[7];
#pragma unroll
  for (int j = -3; j <= 3; ++j) {
    const int ls = l + j;
    xv[j + 3] = ((unsigned)ls < LSEQ) ? xin[ls] : 0.f;
  }
  float af = cb_f[d], ab = cb_b[d];
#pragma unroll
  for (int j = 0; j < 4; ++j) {
    af = fmaf(cw_f[d * 4 + j], xv[j], af);       // x[l-3+j]
    ab = fmaf(cw_b[d * 4 + j], xv[6 - j], ab);   // x[l+3-j]
  }
  xc[((size_t)(b)       * 192 + d) * LSEQ + l] = af / (1.f + __expf(-af));
  xc[((size_t)(2 + b)   * 192 + d) * LSEQ + l] = ab / (1.f + __expf(-ab));
}

// ---------------------------------------------------------------------------
// K3b: x_proj + dt_proj + softplus, fused, k-split across 4 waves.
// Block = 256 thr (4 waves), 64-l tile; wave w covers k in [48w, 48w+48).
// Partials reduced through LDS; BC written coalesced; dt fused.
// __launch_bounds__(256,2): don't squeeze VGPRs (R4's 64-thr version spilled
// acc[38] to scratch, VGPR=28 -> 88us latency-bound disaster).
// ---------------------------------------------------------------------------
__global__ __launch_bounds__(256, 2) void k3b_xproj(const float* __restrict__ xc,
    const float* __restrict__ xwT,
    const float* __restrict__ dtw_f, const float* __restrict__ dtb_f,
    const float* __restrict__ dtw_b, const float* __restrict__ dtb_b,
    float* __restrict__ dt, float* __restrict__ BCo) {
  __shared__ float part[4][38][65];
  __shared__ float sdbl[6][65];
  const int dirb = blockIdx.y, dir = dirb >> 1;
  const int tid = threadIdx.x;
  const int lane = tid & 63, w = tid >> 6;
  const int l0 = blockIdx.x << 6;
  const float* pc = xc + (size_t)dirb * 192 * LSEQ + l0 + lane;
  const float* wt = xwT + dir * 192 * 40;
  float acc[38];
#pragma unroll
  for (int r = 0; r < 38; ++r) acc[r] = 0.f;
  const int kbase = w * 48;
#pragma unroll 2
  for (int kk = 0; kk < 48; ++kk) {
    const int k = kbase + kk;
    const float v = pc[(size_t)k * LSEQ];
    const float* wk = wt + k * 40;
#pragma unroll
    for (int r = 0; r < 38; ++r) acc[r] = fmaf(wk[r], v, acc[r]);
  }
#pragma unroll
  for (int r = 0; r < 38; ++r) part[w][r][lane] = acc[r];
  __syncthreads();
  // --- BC sums: thread t -> (l = t>>2, q-range 8*(t&3)..+8), coalesced 32B/thr
  {
    const int lq = tid >> 2, g = tid & 3;
    float o[8];
#pragma unroll
    for (int i = 0; i < 4; ++i) {
      const int rB = 6 + 4 * g + i, rC = 22 + 4 * g + i;
      float sB = 0.f, sC = 0.f;
#pragma unroll
      for (int ww = 0; ww < 4; ++ww) {
        sB += part[ww][rB][lq];
        sC += part[ww][rC][lq];
      }
      o[2 * i] = sB; o[2 * i + 1] = sC;
    }
    float4* pbc = (float4*)(BCo + ((size_t)dirb * LSEQ + l0 + lq) * 32 + 8 * g);
    pbc[0] = make_float4(o[0], o[1], o[2], o[3]);
    pbc[1] = make_float4(o[4], o[5], o[6], o[7]);
  }
  // --- dt-rank sums (r<6) into LDS
  for (int r = w; r < 6; r += 4) {
    float s = 0.f;
#pragma unroll
    for (int ww = 0; ww < 4; ++ww) s += part[ww][r][lane];
    sdbl[r][lane] = s;
  }
  __syncthreads();
  // --- dt_proj + softplus: wave w covers d in [48w, 48w+48)
  const float* dw = dir ? dtw_b : dtw_f;
  const float* db = dir ? dtb_b : dtb_f;
  const float v0 = sdbl[0][lane], v1 = sdbl[1][lane], v2 = sdbl[2][lane],
              v3 = sdbl[3][lane], v4 = sdbl[4][lane], v5 = sdbl[5][lane];
  float* pdt = dt + (size_t)dirb * 192 * LSEQ + l0 + lane;
#pragma unroll 2
  for (int i = 0; i < 48; ++i) {
    const int d = w * 48 + i;
    float s = db[d];
    s = fmaf(dw[d * 6 + 0], v0, s);
    s = fmaf(dw[d * 6 + 1], v1, s);
    s = fmaf(dw[d * 6 + 2], v2, s);
    s = fmaf(dw[d * 6 + 3], v3, s);
    s = fmaf(dw[d * 6 + 4], v4, s);
    s = fmaf(dw[d * 6 + 5], v5, s);
    pdt[(size_t)d * LSEQ] = (s > 20.f) ? s : __logf(1.f + __expf(s));
  }
}

// ---------------------------------------------------------------------------
// Scan pass A: per-chunk decay product P=exp(Adn*Σdt) and local end-state.
// dt and xc staged from global; (dt, dt*xc) packed into LDS at stage time.
// ---------------------------------------------------------------------------
template<int DIR>
__device__ __forceinline__ void scanA_body(
    float2 (*sdt)[16][34], float2 (*sbc)[TS][16],
    const float* __restrict__ dtg, const float* __restrict__ xcg,
    const float2* __restrict__ pbc, const float* __restrict__ Al,
    float* __restrict__ Pb, float* __restrict__ Hb, int b, int c, int dg) {
  const int tid = threadIdx.x;
  const int dl = tid >> 4, n = tid & 15;
  const int dirb = DIR * 2 + b;
  const int d = (dg << 4) + dl;
  const float Adn = -__expf(Al[d * 16 + n]);
  const float* dtp = dtg + ((size_t)(dirb * 192) + d) * LSEQ;
  const float* xcp = xcg + ((size_t)(dirb * 192) + d) * LSEQ;
  const int c0 = c << 8;
  const int tl2 = (tid & 15) * 2;
  const int br = tid >> 3, bcc = (tid & 7) * 2;
  {
    const int t0 = c0 + (DIR ? (NST - 1) : 0) * TS;
    const float2 a  = *(const float2*)&dtp[t0 + tl2];
    const float2 xu = *(const float2*)&xcp[t0 + tl2];
    const float4 rbc = *(const float4*)&pbc[(size_t)(t0 + br) * 16 + bcc];
    float4 pk; pk.x = a.x; pk.y = a.x * xu.x; pk.z = a.y; pk.w = a.y * xu.y;
    *(float4*)&sdt[0][dl][tl2] = pk;
    *(float4*)&sbc[0][br][bcc] = rbc;
  }
  __syncthreads();
  float h = 0.f, dts = 0.f;
  int buf = 0;
  for (int i = 0; i < NST; ++i) {
    const int s = DIR ? (NST - 1 - i) : i;
    float2 a = make_float2(0.f, 0.f), xu = make_float2(0.f, 0.f);
    float4 rbc = make_float4(0.f, 0.f, 0.f, 0.f);
    if (i + 1 < NST) {
      const int t0n = c0 + (DIR ? (s - 1) : (s + 1)) * TS;
      a   = *(const float2*)&dtp[t0n + tl2];
      xu  = *(const float2*)&xcp[t0n + tl2];
      rbc = *(const float4*)&pbc[(size_t)(t0n + br) * 16 + bcc];
    }
#pragma unroll
    for (int tt = 0; tt < TS; ++tt) {
      const int t = DIR ? (TS - 1 - tt) : tt;
      const float2 xv = sdt[buf][dl][t];
      const float Bn = sbc[buf][t][n].x;
      const float av = __expf(xv.x * Adn);
      h = fmaf(av, h, xv.y * Bn);
      dts += xv.x;
    }
    if (i + 1 < NST) {
      float4 pk; pk.x = a.x; pk.y = a.x * xu.x; pk.z = a.y; pk.w = a.y * xu.y;
      *(float4*)&sdt[buf ^ 1][dl][tl2] = pk;
      *(float4*)&sbc[buf ^ 1][br][bcc] = rbc;
    }
    __syncthreads();
    buf ^= 1;
  }
  const int o = ((dirb * 32 + c) * 192 + d) * 16 + n;
  Pb[o] = __expf(dts * Adn);
  Hb[o] = h;
}

__global__ __launch_bounds__(256) void k4_scanA(const float* __restrict__ dtg,
    const float* __restrict__ xcg, const float2* __restrict__ bc2,
    const float* __restrict__ Al_f, const float* __restrict__ Al_b,
    float* __restrict__ Pb, float* __restrict__ Hb) {
  __shared__ float2 sdt[2][16][34];
  __shared__ float2 sbc[2][TS][16];
  const int b = blockIdx.y, c = blockIdx.x & 31, dg = blockIdx.x >> 5;
  const float2* pbc0 = bc2 + (size_t)(0 * 2 + b) * LSEQ * 16;
  const float2* pbc1 = bc2 + (size_t)(1 * 2 + b) * LSEQ * 16;
  if (blockIdx.z == 0) scanA_body<0>(sdt, sbc, dtg, xcg, pbc0, Al_f, Pb, Hb, b, c, dg);
  else                 scanA_body<1>(sdt, sbc, dtg, xcg, pbc1, Al_b, Pb, Hb, b, c, dg);
}

// ---------------------------------------------------------------------------
// K5: chunk-level prefix over 32 chunks
// ---------------------------------------------------------------------------
__global__ __launch_bounds__(256) void k5_scanB(const float* __restrict__ Pb,
    const float* __restrict__ Hb, float* __restrict__ H0) {
  const int g = blockIdx.x * 256 + threadIdx.x;
  const int dirb = g / 3072, dn = g - dirb * 3072;
  const int dir = dirb >> 1;
  const int base = dirb * (32 * 3072) + dn;
  float h = 0.f;
  if (dir == 0) {
    for (int c = 0; c < 32; ++c) {
      const int o = base + c * 3072;
      H0[o] = h;
      h = fmaf(Pb[o], h, Hb[o]);
    }
  } else {
    for (int c = 31; c >= 0; --c) {
      const int o = base + c * 3072;
      H0[o] = h;
      h = fmaf(Pb[o], h, Hb[o]);
    }
  }
}

// ---------------------------------------------------------------------------
// Scan pass C: replay with correct h0; DPP reduce; y = (p + D*xc)*silu(z).
// ---------------------------------------------------------------------------
template<int DIR>
__device__ __forceinline__ void scanC_body(
    float2 (*sdt)[16][34], float2 (*sbc)[TS][16],
    const float* __restrict__ dtg, const float* __restrict__ xcg,
    const float2* __restrict__ pbc, const float* __restrict__ xz,
    const float* __restrict__ Al, const float* __restrict__ Dv_,
    const float* __restrict__ H0, float* __restrict__ yout,
    int b, int c, int dg) {
  const int tid = threadIdx.x;
  const int dl = tid >> 4, n = tid & 15;
  const int dirb = DIR * 2 + b;
  const int d = (dg << 4) + dl;
  const float Adn = -__expf(Al[d * 16 + n]);
  const float Dv = Dv_[d];
  const float* dtp = dtg + ((size_t)(dirb * 192) + d) * LSEQ;
  const float* xcp = xcg + ((size_t)(dirb * 192) + d) * LSEQ;
  const float* psp = xz + ((size_t)(b * 384) + 192 + d) * LSEQ;
  float* py = yout + ((size_t)(b * 192) + d) * LSEQ;
  const int o = ((dirb * 32 + c) * 192 + d) * 16 + n;
  const int c0 = c << 8;
  const int tl2 = (tid & 15) * 2;
  const int br = tid >> 3, bcc = (tid & 7) * 2;
  float h = H0[o];
  const int t00 = c0 + (DIR ? (NST - 1) : 0) * TS;
  {
    const float2 a  = *(const float2*)&dtp[t00 + tl2];
    const float2 xu = *(const float2*)&xcp[t00 + tl2];
    const float4 rbc = *(const float4*)&pbc[(size_t)(t00 + br) * 16 + bcc];
    float4 pk; pk.x = a.x; pk.y = a.x * xu.x; pk.z = a.y; pk.w = a.y * xu.y;
    *(float4*)&sdt[0][dl][tl2] = pk;
    *(float4*)&sbc[0][br][bcc] = rbc;
  }
  float cxa = xcp[t00 + n], cxb = xcp[t00 + 16 + n];
  float cspa = psp[t00 + n], cspb = psp[t00 + 16 + n];
  __syncthreads();
  int buf = 0;
  for (int i = 0; i < NST; ++i) {
    const int s = DIR ? (NST - 1 - i) : i;
    const int t0 = c0 + s * TS;
    float2 a = make_float2(0.f, 0.f), xu = make_float2(0.f, 0.f);
    float4 rbc = make_float4(0.f, 0.f, 0.f, 0.f);
    float nxa = 0.f, nxb = 0.f, nspa = 0.f, nspb = 0.f;
    if (i + 1 < NST) {
      const int t0n = c0 + (DIR ? (s - 1) : (s + 1)) * TS;
      a   = *(const float2*)&dtp[t0n + tl2];
      xu  = *(const float2*)&xcp[t0n + tl2];
      rbc = *(const float4*)&pbc[(size_t)(t0n + br) * 16 + bcc];
      nxa = xcp[t0n + n]; nxb = xcp[t0n + 16 + n];
      nspa = psp[t0n + n]; nspb = psp[t0n + 16 + n];
    }
    float p0 = 0.f, p1 = 0.f;
#pragma unroll
    for (int tt = 0; tt < TS; ++tt) {
      const int t = DIR ? (TS - 1 - tt) : tt;
      const float2 xv = sdt[buf][dl][t];
      const float2 v = sbc[buf][t][n];
      const float av = __expf(xv.x * Adn);
      h = fmaf(av, h, xv.y * v.x);
      float p = red16(h * v.y);
      if (t < 16) p0 = ((t & 15) == n) ? p : p0;
      else        p1 = ((t & 15) == n) ? p : p1;
    }
    py[t0 + n]      = fmaf(Dv, cxa, p0) * cspa;
    py[t0 + 16 + n] = fmaf(Dv, cxb, p1) * cspb;
    if (i + 1 < NST) {
      float4 pk; pk.x = a.x; pk.y = a.x * xu.x; pk.z = a.y; pk.w = a.y * xu.y;
      *(float4*)&sdt[buf ^ 1][dl][tl2] = pk;
      *(float4*)&sbc[buf ^ 1][br][bcc] = rbc;
      cxa = nxa; cxb = nxb; cspa = nspa; cspb = nspb;
    }
    __syncthreads();
    buf ^= 1;
  }
}

__global__ __launch_bounds__(256) void k6_scanC(const float* __restrict__ dtg,
    const float* __restrict__ xcg, const float2* __restrict__ bc2,
    const float* __restrict__ xz, const float* __restrict__ Al_f,
    const float* __restrict__ Al_b, const float* __restrict__ D_f,
    const float* __restrict__ D_b, const float* __restrict__ H0,
    float* __restrict__ yf, float* __restrict__ yb) {
  __shared__ float2 sdt[2][16][34];
  __shared__ float2 sbc[2][TS][16];
  const int b = blockIdx.y, c = blockIdx.x & 31, dg = blockIdx.x >> 5;
  const float2* pbc0 = bc2 + (size_t)(0 * 2 + b) * LSEQ * 16;
  const float2* pbc1 = bc2 + (size_t)(1 * 2 + b) * LSEQ * 16;
  if (blockIdx.z == 0)
    scanC_body<0>(sdt, sbc, dtg, xcg, pbc0, xz, Al_f, D_f, H0, yf, b, c, dg);
  else
    scanC_body<1>(sdt, sbc, dtg, xcg, pbc1, xz, Al_b, D_b, H0, yb, b, c, dg);
}

// ---------------------------------------------------------------------------
// K7: out_proj GEMM (K=192, N=96) over yf+yb, then inverse serpentine scatter.
// ---------------------------------------------------------------------------
__global__ __launch_bounds__(256) void k7_outproj(const float* __restrict__ yf,
    const float* __restrict__ yb, const float* __restrict__ W,
    float* __restrict__ out) {
  const int m0 = blockIdx.x << 6;
  const int b = m0 >> 13, l0 = m0 & (LSEQ - 1);
  __shared__ float As[32][66];
  __shared__ float Ws[96][33];
  const int tid = threadIdx.x;
  const int tx = tid & 15, ty = tid >> 4;
  const int la = tx << 2;
  float acc[6][4] = {};
  for (int kc = 0; kc < 192; kc += 32) {
    for (int idx = tid; idx < 32 * 64; idx += 256) {
      const int k = idx >> 6, l = idx & 63;
      const size_t off = ((size_t)b * 192 + kc + k) * LSEQ + l0 + l;
      As[k][l] = yf[off] + yb[off];
    }
    for (int idx = tid; idx < 96 * 32; idx += 256) {
      const int e = idx >> 5, k = idx & 31;
      Ws[e][k] = W[e * 192 + kc + k];
    }
    __syncthreads();
#pragma unroll
    for (int k = 0; k < 32; ++k) {
      const float a0 = As[k][la], a1 = As[k][la + 1], a2 = As[k][la + 2], a3 = As[k][la + 3];
#pragma unroll
      for (int j = 0; j < 6; ++j) {
        const float w = Ws[ty * 6 + j][k];
        acc[j][0] = fmaf(w, a0, acc[j][0]);
        acc[j][1] = fmaf(w, a1, acc[j][1]);
        acc[j][2] = fmaf(w, a2, acc[j][2]);
        acc[j][3] = fmaf(w, a3, acc[j][3]);
      }
    }
    __syncthreads();
  }
#pragma unroll
  for (int j = 0; j < 6; ++j) {
    const int e = ty * 6 + j;
#pragma unroll
    for (int i = 0; i < 4; ++i) {
      const int l = l0 + la + i;
      const int hh = (l >> 5) & 31, w = l & 31;
      const int lp = (hh & 1) ? (l + 31 - 2 * w) : l;
      out[((size_t)b * 96 + e) * LSEQ + lp] = acc[j][i];
    }
  }
}

// ---------------------------------------------------------------------------
extern "C" void kernel_launch(void* const* d_in, const int* in_sizes, int n_in,
                              void* d_out, int out_size, void* d_ws, size_t ws_size,
                              hipStream_t stream) {
  const float* x     = (const float*)d_in[0];
  const float* ln_g  = (const float*)d_in[1];
  const float* ln_b  = (const float*)d_in[2];
  const float* in_w  = (const float*)d_in[3];
  const float* cw_f  = (const float*)d_in[4];
  const float* cb_f  = (const float*)d_in[5];
  const float* xw_f  = (const float*)d_in[6];
  const float* dtw_f = (const float*)d_in[7];
  const float* dtb_f = (const float*)d_in[8];
  const float* Al_f  = (const float*)d_in[9];
  const float* D_f   = (const float*)d_in[10];
  const float* cw_b  = (const float*)d_in[11];
  const float* cb_b  = (const float*)d_in[12];
  const float* xw_b  = (const float*)d_in[13];
  const float* dtw_b = (const float*)d_in[14];
  const float* dtb_b = (const float*)d_in[15];
  const float* Al_b  = (const float*)d_in[16];
  const float* D_b   = (const float*)d_in[17];
  const float* ow    = (const float*)d_in[18];
  float* out = (float*)d_out;

  float* ws = (float*)d_ws;
  float* xn   = ws; ws += (size_t)16384 * 96;           // 1.57M
  float* xz   = ws; ws += (size_t)2 * 384 * LSEQ;       // 6.29M
  float* xc   = ws; ws += (size_t)4 * 192 * LSEQ;       // 6.29M
  float* dt   = ws; ws += (size_t)4 * 192 * LSEQ;       // 6.29M
  float* BC   = ws; ws += (size_t)4 * LSEQ * 32;        // 1.05M
  float* yf   = ws; ws += (size_t)2 * 192 * LSEQ;       // 3.15M
  float* yb   = ws; ws += (size_t)2 * 192 * LSEQ;       // 3.15M
  float* Pb   = ws; ws += (size_t)4 * 32 * 192 * 16;    // 0.39M
  float* Hb   = ws; ws += (size_t)4 * 32 * 192 * 16;    // 0.39M
  float* H0   = ws; ws += (size_t)4 * 32 * 192 * 16;    // 0.39M
  float* xwT  = ws; ws += (size_t)2 * 192 * 40;         // 15K

  k0_wt<<<dim3(1), dim3(256), 0, stream>>>(xw_f, xw_b, xwT);
  k1_serp_ln<<<dim3(256), dim3(256), 0, stream>>>(x, ln_g, ln_b, xn);
  k2_inproj<<<dim3(256, 6), dim3(256), 0, stream>>>(xn, in_w, xz);
  k3a_conv<<<dim3(32, 192, 2), dim3(256), 0, stream>>>(xz, cw_f, cb_f, cw_b, cb_b, xc);
  k3b_xproj<<<dim3(128, 4), dim3(256), 0, stream>>>(xc, xwT,
      dtw_f, dtb_f, dtw_b, dtb_b, dt, BC);
  k4_scanA<<<dim3(384, 2, 2), dim3(256), 0, stream>>>(dt, xc, (const float2*)BC,
      Al_f, Al_b, Pb, Hb);
  k5_scanB<<<dim3(48), dim3(256), 0, stream>>>(Pb, Hb, H0);
  k6_scanC<<<dim3(384, 2, 2), dim3(256), 0, stream>>>(dt, xc, (const float2*)BC,
      xz, Al_f, Al_b, D_f, D_b, H0, yf, yb);
  k7_outproj<<<dim3(256), dim3(256), 0, stream>>>(yf, yb, ow, out);
}